// Round 2
// baseline (22521.622 us; speedup 1.0000x reference)
//
#include <hip/hip_runtime.h>
#include <hip/hip_bf16.h>

// Persistent LSTM, round 2. B=128,T=1024,V=256,H=512,G=2048.
// 8 batch groups (16 rows) x 32 gate-slice WGs (16 h-elems = 64 gate rows) = 256 WGs.
// Per step per WG: gates(16x64) = h(16x512) @ W_hh_slice^T, mfma 16x16x32 bf16,
// wave q owns gate type q. Sync: monotonic counter per group; h via sc1 (device-scope)
// loads from LLC, publishes via agent atomic 8B stores. No fences, no L2 inv.

#define TT 1024
#define BB 128
#define HH 512
#define VV 256
#define NG 8     // batch groups
#define GM 16    // rows per group
#define NWG 32   // WGs per group
#define NE 16    // h-elems per WG

typedef __attribute__((ext_vector_type(8))) short short8;
typedef __attribute__((ext_vector_type(4))) float f32x4;

__device__ __forceinline__ unsigned short f2bf(float f) {
  __hip_bfloat16 h = __float2bfloat16(f);
  return *reinterpret_cast<unsigned short*>(&h);
}
__device__ __forceinline__ float sigm(float x) { return 1.0f / (1.0f + __expf(-x)); }
__device__ __forceinline__ float tanh_(float x) { return 1.0f - 2.0f / (1.0f + __expf(2.0f * x)); }

__global__ void lstm_init(const int* __restrict__ x, int* __restrict__ x_t,
                          unsigned int* __restrict__ hbuf0, int* __restrict__ counters) {
  int idx = blockIdx.x * 256 + threadIdx.x;      // 0..131071
  int t = idx >> 7, b = idx & 127;
  x_t[idx] = x[b * TT + t];                      // x_t[t][b]
  if (idx < (BB * HH / 2)) hbuf0[idx] = 0u;      // zero h slot 0 (128 KB bf16)
  if (idx < NG) counters[idx] = 0;
}

__launch_bounds__(256, 1)
__global__ void lstm_persist(const int* __restrict__ x_t, const int* __restrict__ x_len,
                             const float* __restrict__ W_ih, const float* __restrict__ W_hh,
                             const float* __restrict__ b_ih, const float* __restrict__ b_hh,
                             float* __restrict__ out,
                             unsigned short* __restrict__ hbuf,  // [2][128][512] bf16 bits
                             int* __restrict__ counters) {       // [8] monotonic
  const int tid = threadIdx.x;
  const int wave = tid >> 6, lane = tid & 63;
  const int g = blockIdx.x >> 5, ig = blockIdx.x & 31;

  __shared__ unsigned short hA[GM * 520];      // staged h slab, padded stride 520
  __shared__ float gates_s[GM * 68];           // [16 b][64 gate cols], pad 68
  __shared__ unsigned long long hstage[64];    // 16 rows x 16 bf16 = 512 B

  const int nn = lane & 15, quad = lane >> 4;

  // ---- persistent W_hh B-fragments: wave = gate q, col n -> grow = q*512+ig*16+n
  short8 bw[16];
  {
    const float* src = W_hh + (wave * HH + ig * NE + nn) * HH + quad * 8;
#pragma unroll
    for (int kt = 0; kt < 16; kt++) {
      const float* s = src + kt * 32;
      short8 v;
#pragma unroll
      for (int j = 0; j < 8; j++) v[j] = (short)f2bf(s[j]);
      bw[kt] = v;
    }
  }

  // ---- cell mapping: thread = (b = tid>>4, e = tid&15), one cell per thread
  const int bc = tid >> 4, ec = tid & 15;
  const int bglob = g * GM + bc;
  const int xl = x_len[bglob];
  float bias[4];
#pragma unroll
  for (int q = 0; q < 4; q++) {
    int grow = q * HH + ig * NE + ec;
    bias[q] = b_ih[grow] + b_hh[grow];
  }
  float hst = 0.0f, cst = 0.0f;
  int* cnt = counters + g;

  // staging map: thread -> (row = tid&15, colchunk = tid>>4) : 32 elems (64 B)
  const int srow = tid & 15, scol = (tid >> 4) * 32;
  const unsigned long long stage_off =
      (unsigned long long)((g * GM + srow) * HH + scol) * 2ull;

  for (int t = 0; t < TT; ++t) {
    const int slot = t & 1;

    // prefetchable per-step inputs (independent of h; fly during the poll)
    const int xv = x_t[t * BB + bglob];
    const float w0 = W_ih[(0 * HH + ig * NE + ec) * VV + xv];
    const float w1 = W_ih[(1 * HH + ig * NE + ec) * VV + xv];
    const float w2 = W_ih[(2 * HH + ig * NE + ec) * VV + xv];
    const float w3 = W_ih[(3 * HH + ig * NE + ec) * VV + xv];

    // 1. wait for h version t (all 32 producers of this group done)
    if (wave == 0) {
      while (__hip_atomic_load(cnt, __ATOMIC_RELAXED, __HIP_MEMORY_SCOPE_AGENT) < NWG * t)
        __builtin_amdgcn_s_sleep(1);
    }
    __syncthreads();

    // 2. stage h slab (16 rows x 512 bf16 = 16 KB) LLC -> LDS via sc1 loads
    {
      unsigned long long gsrc =
          (unsigned long long)(hbuf + (size_t)slot * (BB * HH)) + stage_off;
      short8 t0, t1, t2, t3;
      asm volatile(
          "global_load_dwordx4 %0, %4, off sc1\n\t"
          "global_load_dwordx4 %1, %4, off offset:16 sc1\n\t"
          "global_load_dwordx4 %2, %4, off offset:32 sc1\n\t"
          "global_load_dwordx4 %3, %4, off offset:48 sc1\n\t"
          "s_waitcnt vmcnt(0)"
          : "=&v"(t0), "=&v"(t1), "=&v"(t2), "=&v"(t3)
          : "v"(gsrc)
          : "memory");
      short8* dst = (short8*)(hA + srow * 520 + scol);
      dst[0] = t0; dst[1] = t1; dst[2] = t2; dst[3] = t3;
    }
    __syncthreads();

    // 3. gates = h @ W_hh_slice^T for this wave's gate type (16x16, K=512)
    f32x4 acc = {0.f, 0.f, 0.f, 0.f};
    {
      const unsigned short* ap = hA + nn * 520 + quad * 8;
      short8 a[16];
#pragma unroll
      for (int kt = 0; kt < 16; kt++) a[kt] = *(const short8*)(ap + kt * 32);
#pragma unroll
      for (int kt = 0; kt < 16; kt++)
        acc = __builtin_amdgcn_mfma_f32_16x16x32_bf16(a[kt], bw[kt], acc, 0, 0, 0);
    }
#pragma unroll
    for (int r = 0; r < 4; r++)
      gates_s[(quad * 4 + r) * 68 + wave * 16 + nn] = acc[r];  // C: row=quad*4+r, col=n
    __syncthreads();

    // 4. cell update (fp32), one cell per thread
    {
      float gi = gates_s[bc * 68 + 0 * 16 + ec] + w0 + bias[0];
      float gf = gates_s[bc * 68 + 1 * 16 + ec] + w1 + bias[1];
      float gg = gates_s[bc * 68 + 2 * 16 + ec] + w2 + bias[2];
      float go = gates_s[bc * 68 + 3 * 16 + ec] + w3 + bias[3];
      float iv = sigm(gi), fv = sigm(gf), gv = tanh_(gg), ov = sigm(go);
      float cn = fv * cst + iv * gv;
      float hn = ov * tanh_(cn);
      bool act = (t < xl);
      if (act) { cst = cn; hst = hn; }
      ((unsigned short*)hstage)[bc * 16 + ec] = f2bf(hst);
      // out store: all waves except the publisher issue now (off the publish chain)
      if (wave != 0)
        out[((size_t)bglob * TT + t) * HH + ig * NE + ec] = act ? hn : 0.0f;
    }
    __syncthreads();

    // 5. publish h version t+1 (wave 0: 64 lanes x 8 B), then counter
    if (wave == 0) {
      unsigned long long v = hstage[lane];
      int row = lane >> 2, ch = lane & 3;
      unsigned long long* dst = (unsigned long long*)(hbuf
          + (size_t)(slot ^ 1) * (BB * HH) + (g * GM + row) * HH + ig * NE + ch * 4);
      __hip_atomic_store(dst, v, __ATOMIC_RELAXED, __HIP_MEMORY_SCOPE_AGENT);
      asm volatile("s_waitcnt vmcnt(0)" ::: "memory");
      if (lane == 0)
        __hip_atomic_fetch_add(cnt, 1, __ATOMIC_RELAXED, __HIP_MEMORY_SCOPE_AGENT);
      // publisher's deferred out store (after the flag)
      bool act = (t < xl);
      float hn_out;  // recompute select: hst holds frozen h; for !act out is 0
      hn_out = act ? hst : 0.0f;
      out[((size_t)bglob * TT + t) * HH + ig * NE + ec] = hn_out;
    }
  }

  // finals: h_T, c_T fp32
  out[(size_t)BB * TT * HH + (size_t)bglob * HH + ig * NE + ec] = hst;
  out[(size_t)BB * TT * HH + (size_t)BB * HH + (size_t)bglob * HH + ig * NE + ec] = cst;
}

extern "C" void kernel_launch(void* const* d_in, const int* in_sizes, int n_in,
                              void* d_out, int out_size, void* d_ws, size_t ws_size,
                              hipStream_t stream) {
  const int*   x     = (const int*)d_in[0];
  const int*   x_len = (const int*)d_in[1];
  const float* W_ih  = (const float*)d_in[2];
  const float* W_hh  = (const float*)d_in[3];
  const float* b_ih  = (const float*)d_in[4];
  const float* b_hh  = (const float*)d_in[5];
  float* out = (float*)d_out;

  char* ws = (char*)d_ws;
  int* x_t = (int*)ws;                                    // 524288 B
  unsigned short* hbuf = (unsigned short*)(ws + 524288);  // 262144 B (2 slots)
  int* counters = (int*)(ws + 524288 + 262144);           // 32 B

  lstm_init<<<512, 256, 0, stream>>>(x, x_t, (unsigned int*)hbuf, counters);
  lstm_persist<<<256, 256, 0, stream>>>(x_t, x_len, W_ih, W_hh, b_ih, b_hh, out, hbuf, counters);
}

// Round 3
// 5819.489 us; speedup vs baseline: 3.8700x; 3.8700x over previous
//
#include <hip/hip_runtime.h>
#include <hip/hip_bf16.h>

// Persistent LSTM, round 3. B=128,T=1024,V=256,H=512,G=2048.
// 8 batch groups (16 rows) x 8 WGs (64 h-elems = 256 gate rows) = 64 WGs, 256 thr.
// Wave q = gate type q, 4 N-subtiles of 16; W_hh slice in 256 VGPRs (bf16 frags).
// Sync: per-WG flag words on private 128B lines; publish = agent atomic 8B stores
// + own-flag store; consumers poll 8 lines. h reads via sc1 (LLC-direct) loads.

#define TT 1024
#define BB 128
#define HH 512
#define VV 256
#define NGP 8   // batch groups
#define GM 16   // batch rows per group
#define NWG 8   // WGs per group
#define NE 64   // h-elems per WG
#define FSTRIDE 32  // ints per flag (128 B line)

typedef __attribute__((ext_vector_type(8))) short short8;
typedef __attribute__((ext_vector_type(4))) float f32x4;
typedef unsigned long long u64;
typedef unsigned short u16;

__device__ __forceinline__ u16 f2bf(float f) {
  __hip_bfloat16 h = __float2bfloat16(f);
  return *reinterpret_cast<u16*>(&h);
}
__device__ __forceinline__ float sigm(float x) { return 1.0f / (1.0f + __expf(-x)); }
__device__ __forceinline__ float tanh_(float x) { return 1.0f - 2.0f / (1.0f + __expf(2.0f * x)); }

__global__ void lstm_init(const int* __restrict__ x, int* __restrict__ x_t,
                          unsigned int* __restrict__ hbuf0, int* __restrict__ flags) {
  int idx = blockIdx.x * 256 + threadIdx.x;   // 0..131071
  int t = idx >> 7, b = idx & 127;
  x_t[idx] = x[b * TT + t];                   // x_t[t][b]
  if (idx < (BB * HH / 2)) hbuf0[idx] = 0u;   // zero h slot 0 (128 KB bf16)
  if (idx < NGP * NWG * FSTRIDE) flags[idx] = 0;
}

__launch_bounds__(256, 1)
__global__ void lstm_persist(const int* __restrict__ x_t, const int* __restrict__ x_len,
                             const float* __restrict__ W_ih, const float* __restrict__ W_hh,
                             const float* __restrict__ b_ih, const float* __restrict__ b_hh,
                             float* __restrict__ out,
                             u16* __restrict__ hbuf,   // [2][128][512] bf16 bits
                             int* __restrict__ flags) { // [8][8][FSTRIDE]
  const int tid = threadIdx.x;
  const int wave = tid >> 6, lane = tid & 63;
  const int nn = lane & 15, quad = lane >> 4;
  const int g = blockIdx.x >> 3, ig = blockIdx.x & 7;

  __shared__ u16 hA[GM * 520];          // staged h slab 16x512, stride 520
  __shared__ float gates_s[GM * 260];   // [16 b][256 gate cols], stride 260
  __shared__ u16 hstage[GM * NE];       // 16 x 64 bf16 = 2 KB

  // ---- persistent W_hh fragments: wave=q, subtile s, col nn ----
  short8 bw[4][16];
#pragma unroll
  for (int s = 0; s < 4; s++) {
    const float* src = W_hh + (size_t)(wave * HH + ig * NE + s * 16 + nn) * HH + quad * 8;
#pragma unroll
    for (int kt = 0; kt < 16; kt++) {
      const float* p = src + kt * 32;
      short8 v;
#pragma unroll
      for (int j = 0; j < 8; j++) v[j] = (short)f2bf(p[j]);
      bw[s][kt] = v;
    }
  }

  // ---- cell mapping: thread -> (bc = tid>>4, 4 elems at e4=(tid&15)*4) ----
  const int bc = tid >> 4, e4 = (tid & 15) * 4;
  const int bglob = g * GM + bc;
  const int xl = x_len[bglob];
  float bias[4][4];
#pragma unroll
  for (int q = 0; q < 4; q++)
#pragma unroll
    for (int j = 0; j < 4; j++) {
      int grow = q * HH + ig * NE + e4 + j;
      bias[q][j] = b_ih[grow] + b_hh[grow];
    }
  float cst[4] = {0.f, 0.f, 0.f, 0.f}, hst[4] = {0.f, 0.f, 0.f, 0.f};

  // stage map: thread -> row tid>>4, 64 B at ushort col (tid&15)*32
  const int srow = tid >> 4, scol = (tid & 15) * 32;
  const u64 stage_off = (u64)(((g * GM + srow) * HH + scol) * 2);

  int* flmine = flags + (g * NWG + ig) * FSTRIDE;
  const int* flpoll = flags + (g * NWG + (lane & 7)) * FSTRIDE;

  __syncthreads();

  for (int t = 0; t < TT; ++t) {
    const int slot = t & 1;

    // prefetchable per-step inputs (fly during poll)
    const int xv = x_t[t * BB + bglob];
    float w[4][4];
#pragma unroll
    for (int q = 0; q < 4; q++)
#pragma unroll
      for (int j = 0; j < 4; j++)
        w[q][j] = W_ih[(size_t)(q * HH + ig * NE + e4 + j) * VV + xv];

    // 1. poll: all 8 producers of this group published version t (8 spread lines)
    if (wave == 0) {
      while (true) {
        int v = __hip_atomic_load(flpoll, __ATOMIC_RELAXED, __HIP_MEMORY_SCOPE_AGENT);
        if (__all(v >= t)) break;
        __builtin_amdgcn_s_sleep(1);
      }
    }
    __syncthreads();

    // 2. stage h slab (16 x 512 bf16 = 16 KB) LLC -> LDS via sc1 loads
    {
      u64 gsrc = (u64)(hbuf + (size_t)slot * (BB * HH)) + stage_off;
      short8 t0, t1, t2, t3;
      asm volatile(
          "global_load_dwordx4 %0, %4, off sc1\n\t"
          "global_load_dwordx4 %1, %4, off offset:16 sc1\n\t"
          "global_load_dwordx4 %2, %4, off offset:32 sc1\n\t"
          "global_load_dwordx4 %3, %4, off offset:48 sc1\n\t"
          "s_waitcnt vmcnt(0)"
          : "=&v"(t0), "=&v"(t1), "=&v"(t2), "=&v"(t3)
          : "v"(gsrc)
          : "memory");
      short8* dst = (short8*)(hA + srow * 520 + scol);
      dst[0] = t0; dst[1] = t1; dst[2] = t2; dst[3] = t3;
    }
    __syncthreads();

    // 3. gates = h @ W_hh_slice^T : M=16, N=64 (4 subtiles), K=512 per wave
    {
      f32x4 acc[4] = {{0,0,0,0},{0,0,0,0},{0,0,0,0},{0,0,0,0}};
      const u16* ap = hA + nn * 520 + quad * 8;
#pragma unroll
      for (int kt = 0; kt < 16; kt++) {
        short8 a = *(const short8*)(ap + kt * 32);
#pragma unroll
        for (int s = 0; s < 4; s++)
          acc[s] = __builtin_amdgcn_mfma_f32_16x16x32_bf16(a, bw[s][kt], acc[s], 0, 0, 0);
      }
#pragma unroll
      for (int s = 0; s < 4; s++)
#pragma unroll
        for (int r = 0; r < 4; r++)
          gates_s[(quad * 4 + r) * 260 + wave * NE + s * 16 + nn] = acc[s][r];
    }
    __syncthreads();

    // 4. cell update: 4 cells per thread, fp32
    {
      f32x4 G0 = *(const f32x4*)&gates_s[bc * 260 + 0 * NE + e4];
      f32x4 G1 = *(const f32x4*)&gates_s[bc * 260 + 1 * NE + e4];
      f32x4 G2 = *(const f32x4*)&gates_s[bc * 260 + 2 * NE + e4];
      f32x4 G3 = *(const f32x4*)&gates_s[bc * 260 + 3 * NE + e4];
      const bool act = (t < xl);
      f32x4 outv;
#pragma unroll
      for (int j = 0; j < 4; j++) {
        float gi = G0[j] + w[0][j] + bias[0][j];
        float gf = G1[j] + w[1][j] + bias[1][j];
        float gg = G2[j] + w[2][j] + bias[2][j];
        float go = G3[j] + w[3][j] + bias[3][j];
        float iv = sigm(gi), fv = sigm(gf), gv = tanh_(gg), ov = sigm(go);
        float cn = fv * cst[j] + iv * gv;
        float hn = ov * tanh_(cn);
        if (act) { cst[j] = cn; hst[j] = hn; }
        outv[j] = act ? hn : 0.0f;
        hstage[bc * NE + e4 + j] = f2bf(hst[j]);
      }
      *(f32x4*)&out[((size_t)bglob * TT + t) * HH + ig * NE + e4] = outv;
    }
    __syncthreads();

    // 5. publish version t+1 (wave 0: 64 lanes x 32 B), then own flag
    if (wave == 0) {
      const u64* hs = (const u64*)hstage;
      u64 v0 = hs[lane * 4], v1 = hs[lane * 4 + 1], v2 = hs[lane * 4 + 2], v3 = hs[lane * 4 + 3];
      int row = lane >> 2, cin = (lane * 4) & 15;  // chunk-in-row (8B units)
      u64* dst = (u64*)(hbuf + (size_t)(slot ^ 1) * (BB * HH)
                        + (size_t)(g * GM + row) * HH + ig * NE + cin * 4);
      __hip_atomic_store(dst + 0, v0, __ATOMIC_RELAXED, __HIP_MEMORY_SCOPE_AGENT);
      __hip_atomic_store(dst + 1, v1, __ATOMIC_RELAXED, __HIP_MEMORY_SCOPE_AGENT);
      __hip_atomic_store(dst + 2, v2, __ATOMIC_RELAXED, __HIP_MEMORY_SCOPE_AGENT);
      __hip_atomic_store(dst + 3, v3, __ATOMIC_RELAXED, __HIP_MEMORY_SCOPE_AGENT);
      asm volatile("s_waitcnt vmcnt(0)" ::: "memory");
      if (lane == 0)
        __hip_atomic_store(flmine, t + 1, __ATOMIC_RELAXED, __HIP_MEMORY_SCOPE_AGENT);
    }
  }

  // finals: h_T, c_T (fp32), 4 elems per thread
  {
    f32x4 hv, cv;
#pragma unroll
    for (int j = 0; j < 4; j++) { hv[j] = hst[j]; cv[j] = cst[j]; }
    *(f32x4*)&out[(size_t)BB * TT * HH + (size_t)bglob * HH + ig * NE + e4] = hv;
    *(f32x4*)&out[(size_t)BB * TT * HH + (size_t)BB * HH + (size_t)bglob * HH + ig * NE + e4] = cv;
  }
}

extern "C" void kernel_launch(void* const* d_in, const int* in_sizes, int n_in,
                              void* d_out, int out_size, void* d_ws, size_t ws_size,
                              hipStream_t stream) {
  const int*   x     = (const int*)d_in[0];
  const int*   x_len = (const int*)d_in[1];
  const float* W_ih  = (const float*)d_in[2];
  const float* W_hh  = (const float*)d_in[3];
  const float* b_ih  = (const float*)d_in[4];
  const float* b_hh  = (const float*)d_in[5];
  float* out = (float*)d_out;

  char* ws = (char*)d_ws;
  int* x_t = (int*)ws;                            // 524288 B
  u16* hbuf = (u16*)(ws + 524288);                // 262144 B (2 slots)
  int* flags = (int*)(ws + 524288 + 262144);      // 8 KB (64 flags on own lines)

  lstm_init<<<512, 256, 0, stream>>>(x, x_t, (unsigned int*)hbuf, flags);
  lstm_persist<<<64, 256, 0, stream>>>(x_t, x_len, W_ih, W_hh, b_ih, b_hh, out, hbuf, flags);
}